// Round 5
// baseline (120.861 us; speedup 1.0000x reference)
//
#include <hip/hip_runtime.h>
#include <hip/hip_bf16.h>

typedef __attribute__((ext_vector_type(8))) short s8v;
typedef __attribute__((ext_vector_type(4))) short s4v;
typedef __attribute__((ext_vector_type(4))) float f32x4;

#define MFMA_BF16 __builtin_amdgcn_mfma_f32_16x16x32_bf16

__device__ inline void gload_lds16(const __hip_bfloat16* g, __hip_bfloat16* l) {
  __builtin_amdgcn_global_load_lds(
      (const __attribute__((address_space(1))) void*)g,
      (__attribute__((address_space(3))) void*)l, 16, 0, 0);
}

__device__ inline short f2bs(float x) {
  __hip_bfloat16 b = __float2bfloat16(x);
  return *reinterpret_cast<short*>(&b);
}

__device__ inline void storeC(float* p, float v) { *p = v; }
__device__ inline void storeC(__hip_bfloat16* p, float v) { *p = __float2bfloat16(v); }

// ---- prep: (z<16) X[n][c][p] fp32 -> XT[n][p][c] bf16 ; (z==16) weight casts
__global__ __launch_bounds__(256) void prep(const float* __restrict__ X,
                                            __hip_bfloat16* __restrict__ XT,
                                            const float* __restrict__ Wq,
                                            const float* __restrict__ Wv,
                                            const float* __restrict__ Wk,
                                            const float* __restrict__ Wo,
                                            const float* __restrict__ bq,
                                            const float* __restrict__ bv,
                                            __hip_bfloat16* __restrict__ WA,
                                            __hip_bfloat16* __restrict__ WkT,
                                            __hip_bfloat16* __restrict__ WOb,
                                            float* __restrict__ biasKV) {
  const int tid = threadIdx.x;
  if (blockIdx.z == 16) {  // weight casts: 128 blocks x 8 iters x 256 threads
    const int blk = blockIdx.y * 16 + blockIdx.x;
#pragma unroll
    for (int t = 0; t < 8; ++t) {
      const int i = (blk * 8 + t) * 256 + tid;  // < 262144
      WA[i] = __float2bfloat16(Wq[i]);
      WA[262144 + i] = __float2bfloat16(Wv[i]);
      WOb[i] = __float2bfloat16(Wo[i]);
      WkT[i] = __float2bfloat16(Wk[(i & 511) * 512 + (i >> 9)]);
      if (i < 512) { biasKV[i] = bq[i]; biasKV[512 + i] = bv[i]; }
    }
    return;
  }
  __shared__ float tl[64][65];
  const int n = blockIdx.z;
  const int c0 = blockIdx.y * 64, p0 = blockIdx.x * 64;
  const int lr = tid >> 4, lc4 = (tid & 15) * 4;
  const float* Xp = X + ((long)n * 512 + c0) * 1024 + p0;
#pragma unroll
  for (int i = 0; i < 4; ++i) {
    const int ch = i * 16 + lr;
    const float4 v = *(const float4*)&Xp[(long)ch * 1024 + lc4];
    tl[ch][lc4 + 0] = v.x; tl[ch][lc4 + 1] = v.y;
    tl[ch][lc4 + 2] = v.z; tl[ch][lc4 + 3] = v.w;
  }
  __syncthreads();
  __hip_bfloat16* XTp = XT + ((long)n * 1024 + p0) * 512 + c0;
#pragma unroll
  for (int i = 0; i < 4; ++i) {
    const int px = i * 16 + lr;
    s4v o;
#pragma unroll
    for (int e = 0; e < 4; ++e) o[e] = f2bs(tl[lc4 + e][px]);
    *(s4v*)&XTp[(long)px * 512 + lc4] = o;
  }
}

// ---------------- NT GEMM: C[m][n] = sum_k A[m][k]*B[n][k] (+row bias) -----
// 128x(32*NJ) tile, 4 waves (2x2), BK=64, global_load_lds staging.
// SWZ==1: 1-D grid, XCD-contiguous x-tiles (y fastest within an XCD) so the
// 8 m-blocks sharing a B-panel run back-to-back on one XCD's L2.
template <typename OutT, bool BROW, int NJ, int SWZ>
__global__ __launch_bounds__(256) void gemm_nt(
    const __hip_bfloat16* __restrict__ A, long strideA,
    const __hip_bfloat16* __restrict__ B, long strideB,
    OutT* __restrict__ C, long strideC, int K, int ldc,
    const float* __restrict__ brow, long strideBrow) {
  int bx, by, bz;
  if (SWZ == 1) {  // grid = 1024 blocks: 128 x-tiles, 8 y-tiles
    const int id = blockIdx.x;
    const int xcd = id & 7, local = id >> 3;  // 128 blocks per XCD
    bx = xcd * 16 + (local >> 3);
    by = local & 7;
    bz = 0;
  } else {
    bx = blockIdx.x; by = blockIdx.y; bz = blockIdx.z;
  }
  A += bz * strideA;
  B += bz * strideB;
  C += bz * strideC;
  const int m0 = by * 128;
  const int n0 = bx * (32 * NJ);
  const int tid = threadIdx.x;
  const int wid = tid >> 6, lane = tid & 63;
  const int wm = wid >> 1, wn = wid & 1;

  __shared__ __hip_bfloat16 As[128 * 64];
  __shared__ __hip_bfloat16 Bs[32 * NJ * 64];

  f32x4 acc[4][NJ] = {};

  const __hip_bfloat16* gA0 = A + (long)(m0 + wid * 32 + (lane >> 3)) * K + (lane & 7) * 8;
  const __hip_bfloat16* gB0 = B + (long)(n0 + wid * 8 * NJ + (lane >> 3)) * K + (lane & 7) * 8;

  for (int k0 = 0; k0 < K; k0 += 64) {
#pragma unroll
    for (int t = 0; t < 4; ++t)
      gload_lds16(gA0 + (long)t * 8 * K + k0, &As[(wid * 32 + t * 8) * 64]);
#pragma unroll
    for (int t = 0; t < NJ; ++t)
      gload_lds16(gB0 + (long)t * 8 * K + k0, &Bs[(wid * 8 * NJ + t * 8) * 64]);
    __syncthreads();
#pragma unroll
    for (int ks = 0; ks < 2; ++ks) {
      const int koff = ks * 32 + (lane >> 4) * 8;
      s8v a[4], b[NJ];
#pragma unroll
      for (int i = 0; i < 4; ++i)
        a[i] = *(const s8v*)&As[(wm * 64 + i * 16 + (lane & 15)) * 64 + koff];
#pragma unroll
      for (int j = 0; j < NJ; ++j)
        b[j] = *(const s8v*)&Bs[(wn * 16 * NJ + j * 16 + (lane & 15)) * 64 + koff];
#pragma unroll
      for (int i = 0; i < 4; ++i)
#pragma unroll
        for (int j = 0; j < NJ; ++j)
          acc[i][j] = MFMA_BF16(a[i], b[j], acc[i][j], 0, 0, 0);
    }
    __syncthreads();
  }

  const int cr = (lane >> 4) * 4;
  const int cc = lane & 15;
#pragma unroll
  for (int i = 0; i < 4; ++i) {
#pragma unroll
    for (int r = 0; r < 4; ++r) {
      const int gm = m0 + wm * 64 + i * 16 + cr + r;
      const float rb = BROW ? brow[bz * strideBrow + gm] : 0.f;
#pragma unroll
      for (int j = 0; j < NJ; ++j) {
        const int gn = n0 + wn * 16 * NJ + j * 16 + cc;
        storeC(&C[(long)gm * ldc + gn], acc[i][j][r] + rb);
      }
    }
  }
}

// -- Part[b] = V_h K_h^T partial over 512 px, fp32, TRANSPOSED (j-major) ----
// b = (n, h, half); 256 blocks x 8 waves.
__global__ __launch_bounds__(512) void gemm_vkT(const __hip_bfloat16* __restrict__ V,
                                                const __hip_bfloat16* __restrict__ Kk,
                                                float* __restrict__ Part) {
  const int bx = blockIdx.x;
  const int n = bx >> 4, h = (bx >> 1) & 7, half = bx & 1;
  const int tid = threadIdx.x, wid = tid >> 6, lane = tid & 63;
  f32x4 acc[4][4] = {};
  const long colbase = (long)n * 1024 + half * 512 + wid * 64 + (lane >> 4) * 8;
  const __hip_bfloat16* Vb = V + (long)(h * 64 + (lane & 15)) * 16384 + colbase;
  const __hip_bfloat16* Kb = Kk + (long)(h * 64 + (lane & 15)) * 16384 + colbase;
#pragma unroll
  for (int kk = 0; kk < 64; kk += 32) {
    s8v a[4], b[4];
#pragma unroll
    for (int i = 0; i < 4; ++i) a[i] = *(const s8v*)(Vb + (long)i * 16 * 16384 + kk);
#pragma unroll
    for (int j = 0; j < 4; ++j) b[j] = *(const s8v*)(Kb + (long)j * 16 * 16384 + kk);
#pragma unroll
    for (int i = 0; i < 4; ++i)
#pragma unroll
      for (int j = 0; j < 4; ++j) acc[i][j] = MFMA_BF16(a[i], b[j], acc[i][j], 0, 0, 0);
  }
  __shared__ float part[4][4096];
  const int cr = (lane >> 4) * 4, cc = lane & 15;
  if (wid < 4) {
#pragma unroll
    for (int i = 0; i < 4; ++i)
#pragma unroll
      for (int r = 0; r < 4; ++r)
#pragma unroll
        for (int j = 0; j < 4; ++j)
          part[wid][(i * 16 + cr + r) * 64 + j * 16 + cc] = acc[i][j][r];
  }
  __syncthreads();
  if (wid >= 4) {
#pragma unroll
    for (int i = 0; i < 4; ++i)
#pragma unroll
      for (int r = 0; r < 4; ++r)
#pragma unroll
        for (int j = 0; j < 4; ++j)
          part[wid - 4][(i * 16 + cr + r) * 64 + j * 16 + cc] += acc[i][j][r];
  }
  __syncthreads();
  float* outp = Part + (long)bx * 4096;
  for (int e = tid; e < 4096; e += 512) {
    const float sum = part[0][e] + part[1][e] + part[2][e] + part[3][e];
    outp[(e & 63) * 64 + (e >> 6)] = sum;  // transposed: [j][i]
  }
}

// ---- wchain: W''[n] = (Wo * blockdiag(M[n])) * Wk,  b2[n] = W'*bk + bo ----
// block = (c-tile, o-tile, n); per h: stage Mt_h from the two fp32 Part
// halves; MFMA1 C1[j][o]=Mt_h*Wo^T -> W1 (bf16 LDS, XOR-swizzled); MFMA2
// acc += W1 * WkS^T.  c-tile-0 blocks also accumulate b2 from W1.
__global__ __launch_bounds__(256) void wchain(const __hip_bfloat16* __restrict__ WOb,
                                              const __hip_bfloat16* __restrict__ WkT,
                                              const float* __restrict__ Part,
                                              const float* __restrict__ bk,
                                              const float* __restrict__ bo,
                                              __hip_bfloat16* __restrict__ WPP,
                                              float* __restrict__ b2out) {
  const int c0 = blockIdx.x * 128, o0 = blockIdx.y * 128, n = blockIdx.z;
  const int tid = threadIdx.x, wid = tid >> 6, lane = tid & 63;
  const int wm = wid >> 1, wn = wid & 1;
  const int cr = (lane >> 4) * 4, cc = lane & 15;

  __shared__ __hip_bfloat16 WoS[128 * 64];
  __shared__ __hip_bfloat16 WkS[128 * 64];
  __shared__ __hip_bfloat16 MtS[64 * 64];
  __shared__ __hip_bfloat16 W1S[128 * 64];
  __shared__ float bkS[512];

  if (tid < 128) *(float4*)&bkS[tid * 4] = *(const float4*)&bk[tid * 4];

  f32x4 acc2[4][4] = {};
  float bacc = 0.f;
  const int r8 = lane >> 3, b8 = (lane & 7) * 8;

  for (int h = 0; h < 8; ++h) {
    // ---- stage Wo / WkT head-slices (128 rows x 64)
#pragma unroll
    for (int t = 0; t < 4; ++t) {
      const int row = wid * 32 + t * 8;
      gload_lds16(WOb + (long)(o0 + row + r8) * 512 + h * 64 + b8, &WoS[row * 64]);
      gload_lds16(WkT + (long)(c0 + row + r8) * 512 + h * 64 + b8, &WkS[row * 64]);
    }
    // ---- stage Mt_h = Part[n,h,0] + Part[n,h,1], fp32 -> bf16
    {
      const float* P0 = Part + (long)((n * 8 + h) * 2) * 4096;
#pragma unroll
      for (int q = 0; q < 4; ++q) {
        const int e = tid * 16 + q * 4;
        const float4 a = *(const float4*)&P0[e];
        const float4 b = *(const float4*)&P0[4096 + e];
        s4v o;
        o[0] = f2bs(a.x + b.x); o[1] = f2bs(a.y + b.y);
        o[2] = f2bs(a.z + b.z); o[3] = f2bs(a.w + b.w);
        *(s4v*)&MtS[e] = o;
      }
    }
    __syncthreads();  // stage complete

    // ---- stage 1: C1[j][o] = Mt_h x Wo^T  (K=64) -> W1S[o][j] (swizzled)
    f32x4 acc1[2][4] = {};
#pragma unroll
    for (int ks = 0; ks < 2; ++ks) {
      const int ko = ks * 32 + (lane >> 4) * 8;
      s8v aj[2], bw[4];
#pragma unroll
      for (int i = 0; i < 2; ++i)
        aj[i] = *(const s8v*)&MtS[(wn * 32 + i * 16 + cc) * 64 + ko];
#pragma unroll
      for (int t = 0; t < 4; ++t)
        bw[t] = *(const s8v*)&WoS[(wm * 64 + t * 16 + cc) * 64 + ko];
#pragma unroll
      for (int i = 0; i < 2; ++i)
#pragma unroll
        for (int t = 0; t < 4; ++t)
          acc1[i][t] = MFMA_BF16(aj[i], bw[t], acc1[i][t], 0, 0, 0);
    }
#pragma unroll
    for (int i = 0; i < 2; ++i)
#pragma unroll
      for (int t = 0; t < 4; ++t) {
        const int o = wm * 64 + t * 16 + cc;       // C1 col
        const int jb = wn * 32 + i * 16 + cr;      // C1 rows (4 contig j)
        s4v p;
#pragma unroll
        for (int r = 0; r < 4; ++r) p[r] = f2bs(acc1[i][t][r]);
        *(s4v*)((char*)W1S + ((o * 128 + jb * 2) ^ ((o & 7) << 4))) = p;
      }
    __syncthreads();  // W1 ready

    // ---- stage 2: acc2 += W1(128x64) x WkS^T  (K=64)
#pragma unroll
    for (int ks = 0; ks < 2; ++ks) {
      const int ko = ks * 32 + (lane >> 4) * 8;
      s8v a2[4], bw[4];
#pragma unroll
      for (int i = 0; i < 4; ++i) {
        const int o = wm * 64 + i * 16 + cc;
        a2[i] = *(const s8v*)((char*)W1S + ((o * 128 + ko * 2) ^ ((o & 7) << 4)));
      }
#pragma unroll
      for (int t = 0; t < 4; ++t)
        bw[t] = *(const s8v*)&WkS[(wn * 64 + t * 16 + cc) * 64 + ko];
#pragma unroll
      for (int i = 0; i < 4; ++i)
#pragma unroll
        for (int t = 0; t < 4; ++t)
          acc2[i][t] = MFMA_BF16(a2[i], bw[t], acc2[i][t], 0, 0, 0);
    }

    // ---- b2 partial: sum_j W1[o][j]*bk[h*64+j]   (c-tile-0 blocks only)
    if (c0 == 0) {
      const int o = tid >> 1, half = tid & 1;
      float s = 0.f;
#pragma unroll
      for (int q = 0; q < 4; ++q) {
        const int jb = half * 64 + q * 16;  // byte offset in row
        const s8v w = *(const s8v*)((char*)W1S + ((o * 128 + jb) ^ ((o & 7) << 4)));
        const __hip_bfloat16* wb = (const __hip_bfloat16*)&w;
#pragma unroll
        for (int e = 0; e < 8; ++e)
          s += __bfloat162float(wb[e]) * bkS[h * 64 + half * 32 + q * 8 + e];
      }
      bacc += s;
    }
    __syncthreads();  // protect WkS/W1S before next-h staging
  }

  // ---- epilogue
#pragma unroll
  for (int i = 0; i < 4; ++i)
#pragma unroll
    for (int r = 0; r < 4; ++r)
#pragma unroll
      for (int t = 0; t < 4; ++t)
        WPP[((long)n * 512 + o0 + wm * 64 + i * 16 + cr + r) * 512 +
            c0 + wn * 64 + t * 16 + cc] = __float2bfloat16(acc2[i][t][r]);
  if (c0 == 0) {
    const float tot = bacc + __shfl_xor(bacc, 1);
    if ((tid & 1) == 0) {
      const int o = tid >> 1;
      b2out[n * 512 + o0 + o] = tot + bo[o0 + o];
    }
  }
}

// -------- GroupNorm(128 groups of 4ch x 1024px) + affine + X (Y is bf16) ---
__global__ __launch_bounds__(256) void gn_res(const __hip_bfloat16* __restrict__ Y,
                                              const float* __restrict__ X,
                                              const float* __restrict__ gw,
                                              const float* __restrict__ gb,
                                              float* __restrict__ out) {
  const int n = blockIdx.x >> 7, g = blockIdx.x & 127;
  const long base = ((long)n * 512 + g * 4) * 1024;
  const int tid = threadIdx.x;
  float v[16];
  float s = 0.f, s2 = 0.f;
#pragma unroll
  for (int i = 0; i < 2; ++i) {
    const s8v x = *(const s8v*)&Y[base + ((long)(i * 256 + tid)) * 8];
#pragma unroll
    for (int e = 0; e < 8; ++e) {
      const float f = __bfloat162float(((const __hip_bfloat16*)&x)[e]);
      v[i * 8 + e] = f;
      s += f;
      s2 += f * f;
    }
  }
#pragma unroll
  for (int off = 32; off; off >>= 1) {
    s += __shfl_down(s, off);
    s2 += __shfl_down(s2, off);
  }
  __shared__ float rs[8];
  const int wid = tid >> 6, lane = tid & 63;
  if (lane == 0) { rs[wid] = s; rs[4 + wid] = s2; }
  __syncthreads();
  if (tid == 0) {
    const float ts = rs[0] + rs[1] + rs[2] + rs[3];
    const float t2 = rs[4] + rs[5] + rs[6] + rs[7];
    const float mu = ts * (1.f / 4096.f);
    const float var = t2 * (1.f / 4096.f) - mu * mu;
    rs[0] = mu;
    rs[1] = rsqrtf(var + 1e-5f);
  }
  __syncthreads();
  const float mu = rs[0], rstd = rs[1];
#pragma unroll
  for (int i = 0; i < 2; ++i) {
    const int chunk = i * 256 + tid;
    const long e0 = base + (long)chunk * 8;
    const int c = g * 4 + (chunk >> 7);
    const float sc = rstd * gw[c], sh = gb[c];
    const float4 x0 = *(const float4*)&X[e0];
    const float4 x1 = *(const float4*)&X[e0 + 4];
    float4 o0, o1;
    o0.x = (v[i * 8 + 0] - mu) * sc + sh + x0.x;
    o0.y = (v[i * 8 + 1] - mu) * sc + sh + x0.y;
    o0.z = (v[i * 8 + 2] - mu) * sc + sh + x0.z;
    o0.w = (v[i * 8 + 3] - mu) * sc + sh + x0.w;
    o1.x = (v[i * 8 + 4] - mu) * sc + sh + x1.x;
    o1.y = (v[i * 8 + 5] - mu) * sc + sh + x1.y;
    o1.z = (v[i * 8 + 6] - mu) * sc + sh + x1.z;
    o1.w = (v[i * 8 + 7] - mu) * sc + sh + x1.w;
    *(float4*)&out[e0] = o0;
    *(float4*)&out[e0 + 4] = o1;
  }
}

extern "C" void kernel_launch(void* const* d_in, const int* in_sizes, int n_in,
                              void* d_out, int out_size, void* d_ws, size_t ws_size,
                              hipStream_t stream) {
  const float* X  = (const float*)d_in[0];
  const float* Wq = (const float*)d_in[1];
  const float* bq = (const float*)d_in[2];
  const float* Wk = (const float*)d_in[3];
  const float* bk = (const float*)d_in[4];
  const float* Wv = (const float*)d_in[5];
  const float* bv = (const float*)d_in[6];
  const float* Wo = (const float*)d_in[7];
  const float* bo = (const float*)d_in[8];
  const float* gw = (const float*)d_in[9];
  const float* gb = (const float*)d_in[10];
  float* out = (float*)d_out;

  char* ws = (char*)d_ws;
  __hip_bfloat16* XT   = (__hip_bfloat16*)(ws + 0);          // 16 MiB [16384][512]
  __hip_bfloat16* KV   = (__hip_bfloat16*)(ws + 16777216);   // 32 MiB [1024][16384]
  __hip_bfloat16* Y    = (__hip_bfloat16*)(ws + 16777216);   // 16 MiB, overlays KV
  __hip_bfloat16* WPP  = (__hip_bfloat16*)(ws + 58720256);   // 8 MiB  W'' [16][512][512]
  float*          Part = (float*)(ws + 67108864);            // 4 MiB  [256][64][64] fp32
  __hip_bfloat16* WA   = (__hip_bfloat16*)(ws + 71303168);   // 1 MiB  [Wq;Wv]
  __hip_bfloat16* WkT  = (__hip_bfloat16*)(ws + 72351744);   // 0.5 MiB
  __hip_bfloat16* WOb  = (__hip_bfloat16*)(ws + 72876032);   // 0.5 MiB
  float*          bKV  = (float*)(ws + 73400320);            // [1024]
  float*          b2   = (float*)(ws + 73404416);            // [16][512] fp32

  // 1. X -> XT (bf16 [n][p][c]) + weight casts, one dispatch
  prep<<<dim3(16, 8, 17), 256, 0, stream>>>(X, XT, Wq, Wv, Wk, Wo, bq, bv,
                                            WA, WkT, WOb, bKV);
  // 2. KV[1024][16384] = [Wq;Wv] * XT^T + [bq;bv]  (XCD-contiguous swizzle)
  gemm_nt<__hip_bfloat16, true, 4, 1><<<1024, 256, 0, stream>>>(
      WA, 0, XT, 0, KV, 0, 512, 16384, bKV, 0);
  // 3. Part[n,h,half] = (V_h K_h^T)^T partial over 512 px, fp32
  gemm_vkT<<<256, 512, 0, stream>>>(KV + (long)512 * 16384, KV, Part);
  // 4. W'' = (Wo * blockdiag(M)) * Wk, b2 = W'*bk + bo  (fused chain)
  wchain<<<dim3(4, 4, 16), 256, 0, stream>>>(WOb, WkT, Part, bk, bo, WPP, b2);
  // 5. Y[n][512][1024] = W''[n] * XT[n]^T + b2[n]  (bf16, 64-wide N tiles)
  gemm_nt<__hip_bfloat16, true, 2, 0><<<dim3(16, 4, 16), 256, 0, stream>>>(
      WPP, 262144, XT, 524288, Y, 524288, 512, 1024, b2, 512);
  // 6. GroupNorm + affine + residual
  gn_res<<<2048, 256, 0, stream>>>(Y, X, gw, gb, out);
}

// Round 6
// 116.981 us; speedup vs baseline: 1.0332x; 1.0332x over previous
//
#include <hip/hip_runtime.h>
#include <hip/hip_bf16.h>

typedef __attribute__((ext_vector_type(8))) short s8v;
typedef __attribute__((ext_vector_type(4))) short s4v;
typedef __attribute__((ext_vector_type(4))) float f32x4;

#define MFMA_BF16 __builtin_amdgcn_mfma_f32_16x16x32_bf16

__device__ inline void gload_lds16(const __hip_bfloat16* g, __hip_bfloat16* l) {
  __builtin_amdgcn_global_load_lds(
      (const __attribute__((address_space(1))) void*)g,
      (__attribute__((address_space(3))) void*)l, 16, 0, 0);
}

__device__ inline short f2bs(float x) {
  __hip_bfloat16 b = __float2bfloat16(x);
  return *reinterpret_cast<short*>(&b);
}

__device__ inline void storeC(float* p, float v) { *p = v; }
__device__ inline void storeC(__hip_bfloat16* p, float v) { *p = __float2bfloat16(v); }

// ---- prep: (z<16) X[n][c][p] fp32 -> XT[n][p][c] bf16 + Xc[n][c][p] bf16
//      (z==16) weight casts
__global__ __launch_bounds__(256) void prep(const float* __restrict__ X,
                                            __hip_bfloat16* __restrict__ XT,
                                            __hip_bfloat16* __restrict__ Xc,
                                            const float* __restrict__ Wq,
                                            const float* __restrict__ Wv,
                                            const float* __restrict__ Wk,
                                            const float* __restrict__ Wo,
                                            const float* __restrict__ bq,
                                            const float* __restrict__ bv,
                                            __hip_bfloat16* __restrict__ WA,
                                            __hip_bfloat16* __restrict__ WkT,
                                            __hip_bfloat16* __restrict__ WOb,
                                            float* __restrict__ biasKV) {
  const int tid = threadIdx.x;
  if (blockIdx.z == 16) {  // weight casts: 128 blocks x 8 iters x 256 threads
    const int blk = blockIdx.y * 16 + blockIdx.x;
#pragma unroll
    for (int t = 0; t < 8; ++t) {
      const int i = (blk * 8 + t) * 256 + tid;  // < 262144
      WA[i] = __float2bfloat16(Wq[i]);
      WA[262144 + i] = __float2bfloat16(Wv[i]);
      WOb[i] = __float2bfloat16(Wo[i]);
      WkT[i] = __float2bfloat16(Wk[(i & 511) * 512 + (i >> 9)]);
      if (i < 512) { biasKV[i] = bq[i]; biasKV[512 + i] = bv[i]; }
    }
    return;
  }
  __shared__ float tl[64][65];
  const int n = blockIdx.z;
  const int c0 = blockIdx.y * 64, p0 = blockIdx.x * 64;
  const int lr = tid >> 4, lc4 = (tid & 15) * 4;
  const float* Xp = X + ((long)n * 512 + c0) * 1024 + p0;
  __hip_bfloat16* Xcp = Xc + ((long)n * 512 + c0) * 1024 + p0;
#pragma unroll
  for (int i = 0; i < 4; ++i) {
    const int ch = i * 16 + lr;
    const float4 v = *(const float4*)&Xp[(long)ch * 1024 + lc4];
    tl[ch][lc4 + 0] = v.x; tl[ch][lc4 + 1] = v.y;
    tl[ch][lc4 + 2] = v.z; tl[ch][lc4 + 3] = v.w;
    s4v xo;
    xo[0] = f2bs(v.x); xo[1] = f2bs(v.y); xo[2] = f2bs(v.z); xo[3] = f2bs(v.w);
    *(s4v*)&Xcp[(long)ch * 1024 + lc4] = xo;  // straight bf16 copy for residual
  }
  __syncthreads();
  __hip_bfloat16* XTp = XT + ((long)n * 1024 + p0) * 512 + c0;
#pragma unroll
  for (int i = 0; i < 4; ++i) {
    const int px = i * 16 + lr;
    s4v o;
#pragma unroll
    for (int e = 0; e < 4; ++e) o[e] = f2bs(tl[lc4 + e][px]);
    *(s4v*)&XTp[(long)px * 512 + lc4] = o;
  }
}

// ---------------- NT GEMM: C[m][n] = sum_k A[m][k]*B[n][k] (+row bias) -----
// 128x128 tile, 4 waves (2x2), BK=64, global_load_lds staging (m97 structure)
template <typename OutT, bool BROW>
__global__ __launch_bounds__(256) void gemm_nt(
    const __hip_bfloat16* __restrict__ A, long strideA,
    const __hip_bfloat16* __restrict__ B, long strideB,
    OutT* __restrict__ C, long strideC, int K, int ldc,
    const float* __restrict__ brow, long strideBrow) {
  A += blockIdx.z * strideA;
  B += blockIdx.z * strideB;
  C += blockIdx.z * strideC;
  const int m0 = blockIdx.y * 128;
  const int n0 = blockIdx.x * 128;
  const int tid = threadIdx.x;
  const int wid = tid >> 6, lane = tid & 63;
  const int wm = wid >> 1, wn = wid & 1;

  __shared__ __hip_bfloat16 As[128 * 64];
  __shared__ __hip_bfloat16 Bs[128 * 64];

  f32x4 acc[4][4] = {};

  const __hip_bfloat16* gA0 = A + (long)(m0 + wid * 32 + (lane >> 3)) * K + (lane & 7) * 8;
  const __hip_bfloat16* gB0 = B + (long)(n0 + wid * 32 + (lane >> 3)) * K + (lane & 7) * 8;

  for (int k0 = 0; k0 < K; k0 += 64) {
#pragma unroll
    for (int t = 0; t < 4; ++t) {
      gload_lds16(gA0 + (long)t * 8 * K + k0, &As[(wid * 32 + t * 8) * 64]);
      gload_lds16(gB0 + (long)t * 8 * K + k0, &Bs[(wid * 32 + t * 8) * 64]);
    }
    __syncthreads();
#pragma unroll
    for (int ks = 0; ks < 2; ++ks) {
      const int koff = ks * 32 + (lane >> 4) * 8;
      s8v a[4], b[4];
#pragma unroll
      for (int i = 0; i < 4; ++i)
        a[i] = *(const s8v*)&As[(wm * 64 + i * 16 + (lane & 15)) * 64 + koff];
#pragma unroll
      for (int j = 0; j < 4; ++j)
        b[j] = *(const s8v*)&Bs[(wn * 64 + j * 16 + (lane & 15)) * 64 + koff];
#pragma unroll
      for (int i = 0; i < 4; ++i)
#pragma unroll
        for (int j = 0; j < 4; ++j)
          acc[i][j] = MFMA_BF16(a[i], b[j], acc[i][j], 0, 0, 0);
    }
    __syncthreads();
  }

  const int cr = (lane >> 4) * 4;
  const int cc = lane & 15;
#pragma unroll
  for (int i = 0; i < 4; ++i) {
#pragma unroll
    for (int r = 0; r < 4; ++r) {
      const int gm = m0 + wm * 64 + i * 16 + cr + r;
      const float rb = BROW ? brow[blockIdx.z * strideBrow + gm] : 0.f;
#pragma unroll
      for (int j = 0; j < 4; ++j) {
        const int gn = n0 + wn * 64 + j * 16 + cc;
        storeC(&C[(long)gm * ldc + gn], acc[i][j][r] + rb);
      }
    }
  }
}

// -------- Mt[n,h][j][i] = (V_h K_h^T)[i][j] bf16 (K-reduce 1024, 8 waves) --
__global__ __launch_bounds__(512) void gemm_vkT(const __hip_bfloat16* __restrict__ V,
                                                const __hip_bfloat16* __restrict__ Kk,
                                                __hip_bfloat16* __restrict__ Mt) {
  const int n = blockIdx.x >> 3, h = blockIdx.x & 7;
  const int tid = threadIdx.x, wid = tid >> 6, lane = tid & 63;
  f32x4 acc[4][4] = {};
  const long colbase = (long)n * 1024 + wid * 128 + (lane >> 4) * 8;
  const __hip_bfloat16* Vb = V + (long)(h * 64 + (lane & 15)) * 16384 + colbase;
  const __hip_bfloat16* Kb = Kk + (long)(h * 64 + (lane & 15)) * 16384 + colbase;
#pragma unroll
  for (int kk = 0; kk < 128; kk += 32) {
    s8v a[4], b[4];
#pragma unroll
    for (int i = 0; i < 4; ++i) a[i] = *(const s8v*)(Vb + (long)i * 16 * 16384 + kk);
#pragma unroll
    for (int j = 0; j < 4; ++j) b[j] = *(const s8v*)(Kb + (long)j * 16 * 16384 + kk);
#pragma unroll
    for (int i = 0; i < 4; ++i)
#pragma unroll
      for (int j = 0; j < 4; ++j) acc[i][j] = MFMA_BF16(a[i], b[j], acc[i][j], 0, 0, 0);
  }
  __shared__ float part[4][4096];
  const int cr = (lane >> 4) * 4, cc = lane & 15;
  if (wid < 4) {
#pragma unroll
    for (int i = 0; i < 4; ++i)
#pragma unroll
      for (int r = 0; r < 4; ++r)
#pragma unroll
        for (int j = 0; j < 4; ++j)
          part[wid][(i * 16 + cr + r) * 64 + j * 16 + cc] = acc[i][j][r];
  }
  __syncthreads();
  if (wid >= 4) {
#pragma unroll
    for (int i = 0; i < 4; ++i)
#pragma unroll
      for (int r = 0; r < 4; ++r)
#pragma unroll
        for (int j = 0; j < 4; ++j)
          part[wid - 4][(i * 16 + cr + r) * 64 + j * 16 + cc] += acc[i][j][r];
  }
  __syncthreads();
  __hip_bfloat16* outp = Mt + ((long)n * 8 + h) * 4096;
  for (int e = tid; e < 4096; e += 512) {
    const float sum = part[0][e] + part[1][e] + part[2][e] + part[3][e];
    outp[(e & 63) * 64 + (e >> 6)] = __float2bfloat16(sum);  // Mt[j][i]=M[i][j]
  }
}

// ---- wchain: W''[n] = (Wo * blockdiag(M[n])) * Wk,  b2[n] = W'*bk + bo ----
// block = (c-tile, o-tile, n); per h: MFMA1 C1[j][o]=Mt_h*Wo^T -> W1 (=W' slice,
// bf16 in LDS, XOR-swizzled), MFMA2 acc += W1 * WkS^T.  c-tile-0 blocks also
// accumulate b2 from W1.
__global__ __launch_bounds__(256) void wchain(const __hip_bfloat16* __restrict__ WOb,
                                              const __hip_bfloat16* __restrict__ WkT,
                                              const __hip_bfloat16* __restrict__ Mt,
                                              const float* __restrict__ bk,
                                              const float* __restrict__ bo,
                                              __hip_bfloat16* __restrict__ WPP,
                                              float* __restrict__ b2out) {
  const int c0 = blockIdx.x * 128, o0 = blockIdx.y * 128, n = blockIdx.z;
  const int tid = threadIdx.x, wid = tid >> 6, lane = tid & 63;
  const int wm = wid >> 1, wn = wid & 1;
  const int cr = (lane >> 4) * 4, cc = lane & 15;

  __shared__ __hip_bfloat16 WoS[128 * 64];
  __shared__ __hip_bfloat16 WkS[128 * 64];
  __shared__ __hip_bfloat16 MtS[64 * 64];
  __shared__ __hip_bfloat16 W1S[128 * 64];
  __shared__ float bkS[512];

  if (tid < 128) *(float4*)&bkS[tid * 4] = *(const float4*)&bk[tid * 4];

  f32x4 acc2[4][4] = {};
  float bacc = 0.f;
  const int r8 = lane >> 3, b8 = (lane & 7) * 8;

  for (int h = 0; h < 8; ++h) {
    // ---- stage Wo / WkT head-slices (128 rows x 64) + Mt_h (64x64)
#pragma unroll
    for (int t = 0; t < 4; ++t) {
      const int row = wid * 32 + t * 8;
      gload_lds16(WOb + (long)(o0 + row + r8) * 512 + h * 64 + b8, &WoS[row * 64]);
      gload_lds16(WkT + (long)(c0 + row + r8) * 512 + h * 64 + b8, &WkS[row * 64]);
    }
    {
      const __hip_bfloat16* mg = Mt + ((long)n * 8 + h) * 4096;
      gload_lds16(mg + wid * 512 + lane * 8, &MtS[wid * 512]);
      gload_lds16(mg + 2048 + wid * 512 + lane * 8, &MtS[2048 + wid * 512]);
    }
    __syncthreads();  // stage complete (compiler drains vmcnt)

    // ---- stage 1: C1[j][o] = Mt_h x Wo^T  (K=64) -> W1S[o][j] (swizzled)
    f32x4 acc1[2][4] = {};
#pragma unroll
    for (int ks = 0; ks < 2; ++ks) {
      const int ko = ks * 32 + (lane >> 4) * 8;
      s8v aj[2], bw[4];
#pragma unroll
      for (int i = 0; i < 2; ++i)
        aj[i] = *(const s8v*)&MtS[(wn * 32 + i * 16 + cc) * 64 + ko];
#pragma unroll
      for (int t = 0; t < 4; ++t)
        bw[t] = *(const s8v*)&WoS[(wm * 64 + t * 16 + cc) * 64 + ko];
#pragma unroll
      for (int i = 0; i < 2; ++i)
#pragma unroll
        for (int t = 0; t < 4; ++t)
          acc1[i][t] = MFMA_BF16(aj[i], bw[t], acc1[i][t], 0, 0, 0);
    }
#pragma unroll
    for (int i = 0; i < 2; ++i)
#pragma unroll
      for (int t = 0; t < 4; ++t) {
        const int o = wm * 64 + t * 16 + cc;       // C1 col
        const int jb = wn * 32 + i * 16 + cr;      // C1 rows (4 contig j)
        s4v p;
#pragma unroll
        for (int r = 0; r < 4; ++r) p[r] = f2bs(acc1[i][t][r]);
        *(s4v*)((char*)W1S + ((o * 128 + jb * 2) ^ ((o & 7) << 4))) = p;
      }
    __syncthreads();  // W1 ready

    // ---- stage 2: acc2 += W1(128x64) x WkS^T  (K=64)
#pragma unroll
    for (int ks = 0; ks < 2; ++ks) {
      const int ko = ks * 32 + (lane >> 4) * 8;
      s8v a2[4], bw[4];
#pragma unroll
      for (int i = 0; i < 4; ++i) {
        const int o = wm * 64 + i * 16 + cc;
        a2[i] = *(const s8v*)((char*)W1S + ((o * 128 + ko * 2) ^ ((o & 7) << 4)));
      }
#pragma unroll
      for (int t = 0; t < 4; ++t)
        bw[t] = *(const s8v*)&WkS[(wn * 64 + t * 16 + cc) * 64 + ko];
#pragma unroll
      for (int i = 0; i < 4; ++i)
#pragma unroll
        for (int t = 0; t < 4; ++t)
          acc2[i][t] = MFMA_BF16(a2[i], bw[t], acc2[i][t], 0, 0, 0);
    }

    // ---- b2 partial: sum_j W1[o][j]*bk[h*64+j]   (c-tile-0 blocks only)
    if (c0 == 0) {
      const int o = tid >> 1, half = tid & 1;
      float s = 0.f;
#pragma unroll
      for (int q = 0; q < 4; ++q) {
        const int jb = half * 64 + q * 16;  // byte offset in row
        const s8v w = *(const s8v*)((char*)W1S + ((o * 128 + jb) ^ ((o & 7) << 4)));
        const __hip_bfloat16* wb = (const __hip_bfloat16*)&w;
#pragma unroll
        for (int e = 0; e < 8; ++e)
          s += __bfloat162float(wb[e]) * bkS[h * 64 + half * 32 + q * 8 + e];
      }
      bacc += s;
    }
    __syncthreads();  // protect WkS/W1S before next-h staging
  }

  // ---- epilogue
#pragma unroll
  for (int i = 0; i < 4; ++i)
#pragma unroll
    for (int r = 0; r < 4; ++r)
#pragma unroll
      for (int t = 0; t < 4; ++t)
        WPP[((long)n * 512 + o0 + wm * 64 + i * 16 + cr + r) * 512 +
            c0 + wn * 64 + t * 16 + cc] = __float2bfloat16(acc2[i][t][r]);
  if (c0 == 0) {
    const float tot = bacc + __shfl_xor(bacc, 1);
    if ((tid & 1) == 0) {
      const int o = tid >> 1;
      b2out[n * 512 + o0 + o] = tot + bo[o0 + o];
    }
  }
}

// ---- GroupNorm(128 groups of 4ch x 1024px) + affine + Xc (Y, Xc bf16) -----
__global__ __launch_bounds__(256) void gn_res(const __hip_bfloat16* __restrict__ Y,
                                              const __hip_bfloat16* __restrict__ Xc,
                                              const float* __restrict__ gw,
                                              const float* __restrict__ gb,
                                              float* __restrict__ out) {
  const int n = blockIdx.x >> 7, g = blockIdx.x & 127;
  const long base = ((long)n * 512 + g * 4) * 1024;
  const int tid = threadIdx.x;
  float v[16];
  float s = 0.f, s2 = 0.f;
#pragma unroll
  for (int i = 0; i < 2; ++i) {
    const s8v x = *(const s8v*)&Y[base + ((long)(i * 256 + tid)) * 8];
#pragma unroll
    for (int e = 0; e < 8; ++e) {
      const float f = __bfloat162float(((const __hip_bfloat16*)&x)[e]);
      v[i * 8 + e] = f;
      s += f;
      s2 += f * f;
    }
  }
#pragma unroll
  for (int off = 32; off; off >>= 1) {
    s += __shfl_down(s, off);
    s2 += __shfl_down(s2, off);
  }
  __shared__ float rs[8];
  const int wid = tid >> 6, lane = tid & 63;
  if (lane == 0) { rs[wid] = s; rs[4 + wid] = s2; }
  __syncthreads();
  if (tid == 0) {
    const float ts = rs[0] + rs[1] + rs[2] + rs[3];
    const float t2 = rs[4] + rs[5] + rs[6] + rs[7];
    const float mu = ts * (1.f / 4096.f);
    const float var = t2 * (1.f / 4096.f) - mu * mu;
    rs[0] = mu;
    rs[1] = rsqrtf(var + 1e-5f);
  }
  __syncthreads();
  const float mu = rs[0], rstd = rs[1];
#pragma unroll
  for (int i = 0; i < 2; ++i) {
    const int chunk = i * 256 + tid;
    const long e0 = base + (long)chunk * 8;
    const int c = g * 4 + (chunk >> 7);
    const float sc = rstd * gw[c], sh = gb[c];
    const s8v xv = *(const s8v*)&Xc[e0];
    const __hip_bfloat16* xb = (const __hip_bfloat16*)&xv;
    float4 o0, o1;
    o0.x = (v[i * 8 + 0] - mu) * sc + sh + __bfloat162float(xb[0]);
    o0.y = (v[i * 8 + 1] - mu) * sc + sh + __bfloat162float(xb[1]);
    o0.z = (v[i * 8 + 2] - mu) * sc + sh + __bfloat162float(xb[2]);
    o0.w = (v[i * 8 + 3] - mu) * sc + sh + __bfloat162float(xb[3]);
    o1.x = (v[i * 8 + 4] - mu) * sc + sh + __bfloat162float(xb[4]);
    o1.y = (v[i * 8 + 5] - mu) * sc + sh + __bfloat162float(xb[5]);
    o1.z = (v[i * 8 + 6] - mu) * sc + sh + __bfloat162float(xb[6]);
    o1.w = (v[i * 8 + 7] - mu) * sc + sh + __bfloat162float(xb[7]);
    *(float4*)&out[e0] = o0;
    *(float4*)&out[e0 + 4] = o1;
  }
}

extern "C" void kernel_launch(void* const* d_in, const int* in_sizes, int n_in,
                              void* d_out, int out_size, void* d_ws, size_t ws_size,
                              hipStream_t stream) {
  const float* X  = (const float*)d_in[0];
  const float* Wq = (const float*)d_in[1];
  const float* bq = (const float*)d_in[2];
  const float* Wk = (const float*)d_in[3];
  const float* bk = (const float*)d_in[4];
  const float* Wv = (const float*)d_in[5];
  const float* bv = (const float*)d_in[6];
  const float* Wo = (const float*)d_in[7];
  const float* bo = (const float*)d_in[8];
  const float* gw = (const float*)d_in[9];
  const float* gb = (const float*)d_in[10];
  float* out = (float*)d_out;

  char* ws = (char*)d_ws;
  __hip_bfloat16* XT  = (__hip_bfloat16*)(ws + 0);          // 16 MiB [16384][512]
  __hip_bfloat16* KV  = (__hip_bfloat16*)(ws + 16777216);   // 32 MiB [1024][16384]
  __hip_bfloat16* Y   = (__hip_bfloat16*)(ws + 16777216);   // 16 MiB, overlays KV (dead after vkT)
  __hip_bfloat16* WPP = (__hip_bfloat16*)(ws + 58720256);   // 8 MiB  W'' [16][512][512]
  __hip_bfloat16* Mt  = (__hip_bfloat16*)(ws + 67108864);   // 1 MiB  [16][8][64][64]
  __hip_bfloat16* WA  = (__hip_bfloat16*)(ws + 68157440);   // 1 MiB  [Wq;Wv]
  __hip_bfloat16* WkT = (__hip_bfloat16*)(ws + 69206016);   // 0.5 MiB
  __hip_bfloat16* WOb = (__hip_bfloat16*)(ws + 69730304);   // 0.5 MiB
  float*          bKV = (float*)(ws + 70254592);            // [1024]
  float*          b2  = (float*)(ws + 70258688);            // [16][512] fp32
  __hip_bfloat16* Xc  = (__hip_bfloat16*)(ws + 75497472);   // 16 MiB [16][512][1024] bf16

  // 1. X -> XT (bf16 [n][p][c]) + Xc (bf16 [n][c][p]) + weight casts
  prep<<<dim3(16, 8, 17), 256, 0, stream>>>(X, XT, Xc, Wq, Wv, Wk, Wo, bq, bv,
                                            WA, WkT, WOb, bKV);
  // 2. KV[1024][16384] = [Wq;Wv] * XT^T + [bq;bv]
  gemm_nt<__hip_bfloat16, true><<<dim3(128, 8, 1), 256, 0, stream>>>(
      WA, 0, XT, 0, KV, 0, 512, 16384, bKV, 0);
  // 3. Mt[n,h] = (V_h K_h^T)^T, bf16
  gemm_vkT<<<128, 512, 0, stream>>>(KV + (long)512 * 16384, KV, Mt);
  // 4. W'' = (Wo * blockdiag(M)) * Wk, b2 = W'*bk + bo  (fused chain)
  wchain<<<dim3(4, 4, 16), 256, 0, stream>>>(WOb, WkT, Mt, bk, bo, WPP, b2);
  // 5. Y[n][512][1024] = W''[n] * XT[n]^T + b2[n]   (bf16)
  gemm_nt<__hip_bfloat16, true><<<dim3(8, 4, 16), 256, 0, stream>>>(
      WPP, 262144, XT, 524288, Y, 524288, 512, 1024, b2, 512);
  // 6. GroupNorm + affine + residual (bf16 residual read)
  gn_res<<<2048, 256, 0, stream>>>(Y, Xc, gw, gb, out);
}